// Round 15
// baseline (288.204 us; speedup 1.0000x reference)
//
#include <hip/hip_runtime.h>

typedef int intx4 __attribute__((ext_vector_type(4)));

#define GN 4096
#define GK 1024
#define BM 128
#define BN 128
#define BK 128          // K-bytes per LDS tile row -> 8 K-iters, 16 barriers
#define INVT (1.0f/0.03f)
#define QS 24.0f        // int8 quant scale; dots <= 1024*127^2 < 2^24 (fp32-exact)
#define NTILES 528      // 32*33/2 upper-tri tiles per modality
#define NCROSS 1024     // 32*32 cross tiles
#define NBLK (NCROSS + 2 * NTILES)

static __device__ __forceinline__ int q8(float x) {
    int v = __float2int_rn(x * QS);
    return v < -127 ? -127 : (v > 127 ? 127 : v);
}

// One block per index i: int8-quantize post-row i AND brand-row i, both
// inv-norms (of quantized ints) and the cross-diag int dot, single pass.
// Also zeroes accumulators, out, and the gemm completion counter.
__global__ __launch_bounds__(256)
void prep_all(const float* __restrict__ brand, const float* __restrict__ post,
              unsigned char* __restrict__ brandq, unsigned char* __restrict__ postq,
              float* __restrict__ inv_brand, float* __restrict__ inv_post,
              float* __restrict__ dvec, float* __restrict__ accs,
              int* __restrict__ done, float* __restrict__ out) {
    const int i = blockIdx.x, tid = threadIdx.x;
    const int wave = tid >> 6, lane = tid & 63;
    __shared__ float swp[4], swb[4], swd[4];

    float4 pv = ((const float4*)(post  + (size_t)i * GK))[tid];
    float4 bv = ((const float4*)(brand + (size_t)i * GK))[tid];
    int p0 = q8(pv.x), p1 = q8(pv.y), p2 = q8(pv.z), p3 = q8(pv.w);
    int b0 = q8(bv.x), b1 = q8(bv.y), b2 = q8(bv.z), b3 = q8(bv.w);
    ((int*)(postq  + (size_t)i * GK))[tid] =
        (p0 & 255) | ((p1 & 255) << 8) | ((p2 & 255) << 16) | ((p3 & 255) << 24);
    ((int*)(brandq + (size_t)i * GK))[tid] =
        (b0 & 255) | ((b1 & 255) << 8) | ((b2 & 255) << 16) | ((b3 & 255) << 24);

    // per-thread int partials (<= 4*127^2), accumulated as exact-int floats
    float ssp = (float)(p0 * p0 + p1 * p1 + p2 * p2 + p3 * p3);
    float ssb = (float)(b0 * b0 + b1 * b1 + b2 * b2 + b3 * b3);
    float ssd = (float)(p0 * b0 + p1 * b1 + p2 * b2 + p3 * b3);
    #pragma unroll
    for (int off = 32; off > 0; off >>= 1) {
        ssp += __shfl_down(ssp, off);
        ssb += __shfl_down(ssb, off);
        ssd += __shfl_down(ssd, off);
    }
    if (lane == 0) { swp[wave] = ssp; swb[wave] = ssb; swd[wave] = ssd; }
    __syncthreads();
    if (tid == 0) {
        inv_post[i]  = 1.0f / sqrtf(swp[0] + swp[1] + swp[2] + swp[3]);
        inv_brand[i] = 1.0f / sqrtf(swb[0] + swb[1] + swb[2] + swb[3]);
        dvec[i]      = swd[0] + swd[1] + swd[2] + swd[3];
    }
    if (tid == 64) {
        accs[i] = 0.f; accs[GN + i] = 0.f; accs[2 * GN + i] = 0.f; accs[3 * GN + i] = 0.f;
    }
    if (i == 0 && tid == 128) { *done = 0; out[0] = 0.f; }
}

// Unified GEMM dispatch, int8 16x16x64 MFMA (R11-proven structure: 62 us).
// LDS-staged, BK=128 B, 8 K-iters; LDS = 32768 B -> 5 blocks/CU.
// LDS rows = 128 B = 8 chunks of 16 B; chunk c of row r at slot c^(r&7)
// (conflict-free for DMA writes and b128 fragment reads).
// Final loss fused via completion counter: last-arriving block computes it.
__global__ __launch_bounds__(256, 5)
void gemm_all(const unsigned char* __restrict__ postq, const unsigned char* __restrict__ brandq,
              const float* __restrict__ dvec,
              const float* __restrict__ inv_post, const float* __restrict__ inv_brand,
              float* __restrict__ sum_post, float* __restrict__ cnt_post,
              float* __restrict__ sum_brand, float* __restrict__ cnt_brand,
              int* __restrict__ done, float* __restrict__ out) {
    __shared__ __align__(16) unsigned char smem[2 * BM * BK];   // 32 KB; epilogue red alias
    unsigned char* As = smem;
    unsigned char* Bs = smem + BM * BK;

    const int tid = threadIdx.x;
    const int wave = tid >> 6, lane = tid & 63;
    const int wm = (wave >> 1) * 64, wn = (wave & 1) * 64;

    int idx = blockIdx.x;
    const unsigned char *A, *B;
    const float *invA, *invB;
    float *srow, *scol, *crow, *ccol;
    int bm, bn;
    float iaScale;
    bool is_cross, do_cols;

    if (idx < NCROSS) {
        is_cross = true; do_cols = true;
        bm = (idx >> 5) * BM; bn = (idx & 31) * BN;
        A = postq; B = brandq;
        invA = inv_post; invB = inv_brand; iaScale = INVT;
        srow = sum_post; crow = cnt_post; scol = sum_brand; ccol = cnt_brand;
    } else {
        is_cross = false;
        idx -= NCROSS;
        const unsigned char* X; const float* invx; float* sacc;
        if (idx >= NTILES) { idx -= NTILES; X = brandq; invx = inv_brand; sacc = sum_brand; }
        else               {               X = postq;  invx = inv_post;  sacc = sum_post;  }
        int J = (int)((sqrtf(8.f * idx + 1.f) - 1.f) * 0.5f);
        while ((J + 1) * (J + 2) / 2 <= idx) ++J;
        while (J * (J + 1) / 2 > idx) --J;
        const int I = idx - J * (J + 1) / 2;
        bm = I * BM; bn = J * BN;
        A = X; B = X;
        invA = invx; invB = invx; iaScale = 0.8f * INVT;
        srow = sacc; scol = sacc; crow = nullptr; ccol = nullptr;
        do_cols = (I != J);
    }

    const int lrow = lane & 15;
    const int kq = lane >> 4;                 // 0..3

    // DMA: lane l -> strip row l>>3, LDS slot l&7, global chunk (l&7)^((l>>3)&7).
    // Per wave per iter: 4 A-instr + 4 B-instr, each staging 8 rows (1 KB).
    const size_t dma_off = (size_t)(lane >> 3) * GK + (((lane & 7) ^ ((lane >> 3) & 7)) * 16);
    const unsigned char* aSrc = A + (size_t)(bm + wave * 32) * GK + dma_off;
    const unsigned char* bSrc = B + (size_t)(bn + wave * 32) * GK + dma_off;
    unsigned char* aDst = As + (wave * 32) * BK;
    unsigned char* bDst = Bs + (wave * 32) * BK;

    intx4 acc[4][4] = {};
    #pragma unroll 1
    for (int k0 = 0; k0 < GK; k0 += BK) {
        #pragma unroll
        for (int s = 0; s < 4; ++s) {
            __builtin_amdgcn_global_load_lds(
                (const __attribute__((address_space(1))) void*)(aSrc + (size_t)s * 8 * GK + k0),
                (__attribute__((address_space(3))) void*)(aDst + s * 8 * BK), 16, 0, 0);
            __builtin_amdgcn_global_load_lds(
                (const __attribute__((address_space(1))) void*)(bSrc + (size_t)s * 8 * GK + k0),
                (__attribute__((address_space(3))) void*)(bDst + s * 8 * BK), 16, 0, 0);
        }
        __syncthreads();

        #pragma unroll
        for (int h = 0; h < 2; ++h) {
            intx4 bfr[4];
            #pragma unroll
            for (int u = 0; u < 4; ++u) {
                const int m = wn + u * 16 + lrow;
                bfr[u] = *(const intx4*)(Bs + m * BK + (((4 * h + kq) ^ (m & 7)) * 16));
            }
            #pragma unroll
            for (int t = 0; t < 4; ++t) {
                const int m = wm + t * 16 + lrow;
                const intx4 af = *(const intx4*)(As + m * BK + (((4 * h + kq) ^ (m & 7)) * 16));
                #pragma unroll
                for (int u = 0; u < 4; ++u)
                    acc[t][u] = __builtin_amdgcn_mfma_i32_16x16x64_i8(
                        af, bfr[u], acc[t][u], 0, 0, 0);
            }
        }
        __syncthreads();   // also separates last tile reads from epilogue red alias
    }

    // ---- epilogue (C/D: col=lane&15, row=(lane>>4)*4+reg; R11-verified) ----
    const int cn = lane & 15, rq = lane >> 4;
    float ib_c[4], db_c[4];
    #pragma unroll
    for (int u = 0; u < 4; ++u) {
        const int gc = bn + wn + u * 16 + cn;
        ib_c[u] = invB[gc];
        db_c[u] = is_cross ? dvec[gc] : 0.f;
    }

    float csum[4] = {}, ccnt[4] = {};
    float my_rs = 0.f, my_rc = 0.f;
    #pragma unroll
    for (int t = 0; t < 4; ++t) {
        #pragma unroll
        for (int r = 0; r < 4; ++r) {
            const int rl = wm + t * 16 + rq * 4 + r;
            const int grow = bm + rl;
            const float ia = invA[grow] * iaScale;
            float v = 0.f, w = 0.f;
            if (is_cross) {
                const float da = dvec[grow];
                #pragma unroll
                for (int u = 0; u < 4; ++u) {
                    const float s = (float)acc[t][u][r];   // exact int < 2^24
                    const int gcol = bn + wn + u * 16 + cn;
                    const bool diag = (grow == gcol);
                    float e = __expf(s * ia * ib_c[u]);
                    v += e;
                    csum[u] += e;
                    w += (!diag && s > da) ? 1.f : 0.f;
                    ccnt[u] += (!diag && s > db_c[u]) ? 1.f : 0.f;
                }
                w += __shfl_xor(w, 1); w += __shfl_xor(w, 2);
                w += __shfl_xor(w, 4); w += __shfl_xor(w, 8);
            } else {
                #pragma unroll
                for (int u = 0; u < 4; ++u) {
                    const float s = (float)acc[t][u][r];
                    const int gcol = bn + wn + u * 16 + cn;
                    float e = (grow == gcol) ? 1.0f : __expf(s * ia * ib_c[u]);
                    v += e;
                    csum[u] += e;
                }
            }
            v += __shfl_xor(v, 1); v += __shfl_xor(v, 2);
            v += __shfl_xor(v, 4); v += __shfl_xor(v, 8);
            if (cn == ((t << 2) | r)) { my_rs = v; my_rc = w; }
        }
    }

    // reduction scratch aliases the (dead) tile LDS
    float (*redRS)[2] = (float(*)[2])(smem);
    float (*redRC)[2] = (float(*)[2])(smem + 1024);
    float (*redCS)[2] = (float(*)[2])(smem + 2048);
    float (*redCC)[2] = (float(*)[2])(smem + 3072);

    const int rl_local = wm + (cn >> 2) * 16 + rq * 4 + (cn & 3);
    redRS[rl_local][wave & 1] = my_rs;
    redRC[rl_local][wave & 1] = my_rc;

    float my_cs = 0.f, my_cc = 0.f;
    #pragma unroll
    for (int u = 0; u < 4; ++u) {
        float v = csum[u];
        v += __shfl_xor(v, 16); v += __shfl_xor(v, 32);
        if (rq == u) my_cs = v;
        if (is_cross) {
            float w = ccnt[u];
            w += __shfl_xor(w, 16); w += __shfl_xor(w, 32);
            if (rq == u) my_cc = w;
        }
    }
    const int cl_local = wn + rq * 16 + cn;
    redCS[cl_local][wave >> 1] = my_cs;
    redCC[cl_local][wave >> 1] = my_cc;
    __syncthreads();

    if (tid < 128) {
        atomicAdd(&srow[bm + tid], redRS[tid][0] + redRS[tid][1]);
        if (is_cross) atomicAdd(&crow[bm + tid], redRC[tid][0] + redRC[tid][1]);
    } else if (do_cols) {
        const int t2 = tid - 128;
        atomicAdd(&scol[bn + t2], redCS[t2][0] + redCS[t2][1]);
        if (is_cross) atomicAdd(&ccol[bn + t2], redCC[t2][0] + redCC[t2][1]);
    }

    // ---- fused finisher: last block to complete computes the final loss ----
    __threadfence();            // make this block's atomics visible device-wide
    __syncthreads();
    __shared__ int s_last;
    if (tid == 0) s_last = (atomicAdd(done, 1) == NBLK - 1) ? 1 : 0;
    __syncthreads();
    if (s_last) {
        float part = 0.f;
        for (int i = tid; i < GN; i += 256) {
            float sp = __hip_atomic_load(&sum_post[i],  __ATOMIC_RELAXED, __HIP_MEMORY_SCOPE_AGENT);
            float cp = __hip_atomic_load(&cnt_post[i],  __ATOMIC_RELAXED, __HIP_MEMORY_SCOPE_AGENT);
            float sb = __hip_atomic_load(&sum_brand[i], __ATOMIC_RELAXED, __HIP_MEMORY_SCOPE_AGENT);
            float cb = __hip_atomic_load(&cnt_brand[i], __ATOMIC_RELAXED, __HIP_MEMORY_SCOPE_AGENT);
            float dl = dvec[i] * inv_post[i] * inv_brand[i] * INVT;
            float rb = 1.0f / (4096.0f - cb) + 1.0f;
            float rp = 1.0f / (4096.0f - cp) + 1.0f;
            part += 0.5f * (rb * (logf(sb) - dl) + rp * (logf(sp) - dl));
        }
        #pragma unroll
        for (int off = 32; off > 0; off >>= 1) part += __shfl_down(part, off);
        float* redf = (float*)smem;
        if ((tid & 63) == 0) redf[tid >> 6] = part;
        __syncthreads();
        if (tid == 0) out[0] = redf[0] + redf[1] + redf[2] + redf[3];
    }
}

extern "C" void kernel_launch(void* const* d_in, const int* in_sizes, int n_in,
                              void* d_out, int out_size, void* d_ws, size_t ws_size,
                              hipStream_t stream) {
    const float* brand = (const float*)d_in[0];
    const float* post  = (const float*)d_in[1];
    float* out = (float*)d_out;

    char* ws = (char*)d_ws;
    unsigned char* postq  = (unsigned char*)ws;                          // 4 MB
    unsigned char* brandq = postq + (size_t)GN * GK;                     // 4 MB
    float* inv_post  = (float*)(brandq + (size_t)GN * GK);
    float* inv_brand = inv_post + GN;
    float* dvec      = inv_brand + GN;
    float* accs      = dvec + GN;        // [sum_post, sum_brand, cnt_post, cnt_brand]
    float* sum_post  = accs;
    float* sum_brand = accs + GN;
    float* cnt_post  = accs + 2 * GN;
    float* cnt_brand = accs + 3 * GN;
    int*   done      = (int*)(accs + 4 * GN);

    prep_all<<<GN, 256, 0, stream>>>(brand, post, brandq, postq,
                                     inv_brand, inv_post, dvec, accs, done, out);
    gemm_all<<<NBLK, 256, 0, stream>>>(postq, brandq, dvec,
                                       inv_post, inv_brand,
                                       sum_post, cnt_post,
                                       sum_brand, cnt_brand, done, out);
}